// Round 8
// baseline (714.070 us; speedup 1.0000x reference)
//
#include <hip/hip_runtime.h>
#include <stdint.h>

#define NN 50000   // nodes
#define NE 100000  // edges
#define DD 768     // feature dim
#define KC 1536    // concatenated K = 2*DD
#define SCAN_B 196 // ceil(NN/256)
#define BM 128
#define BN 256
#define BK 64
#define NTM 391    // ceil(NN/128)
#define NTN 3      // DD/256

typedef __attribute__((ext_vector_type(8))) __bf16 bf16x8;
typedef __attribute__((ext_vector_type(4))) float floatx4;

static __device__ __forceinline__ float bf2f(unsigned short u) {
    union { unsigned int u; float f; } c; c.u = ((unsigned int)u) << 16; return c.f;
}
static __device__ __forceinline__ unsigned short f2bf(float f) {
    union { float f; unsigned int u; } c; c.f = f;
    return (unsigned short)((c.u + 0x7FFFu + ((c.u >> 16) & 1u)) >> 16);
}

// async global->LDS, 16B per lane; LDS dst = wave-uniform base + lane*16
static __device__ __forceinline__ void gld16(const void* g, void* l) {
    __builtin_amdgcn_global_load_lds(
        (const __attribute__((address_space(1))) unsigned int*)g,
        (__attribute__((address_space(3))) unsigned int*)l, 16, 0, 0);
}

// ---------------- prep kernels ----------------

// x (f32) -> bf16 into right half of Acat1 ([n][768..1535])
__global__ __launch_bounds__(192) void k_convert_x(const float* __restrict__ x,
                                                   unsigned short* __restrict__ acat) {
    const int n = blockIdx.x;
    const int c = threadIdx.x * 4;
    const float4 v = *(const float4*)(x + (size_t)n * DD + c);
    ushort4 o;
    o.x = f2bf(v.x); o.y = f2bf(v.y); o.z = f2bf(v.z); o.w = f2bf(v.w);
    *(ushort4*)(acat + (size_t)n * KC + DD + c) = o;
}

// Bcat[layer][j][k] = k<768 ? Wl[j][k] : Wr[j][k-768]   (bf16)
__global__ __launch_bounds__(384) void k_convert_w(const float* __restrict__ W1l,
                                                   const float* __restrict__ W1r,
                                                   const float* __restrict__ W2l,
                                                   const float* __restrict__ W2r,
                                                   unsigned short* __restrict__ B1,
                                                   unsigned short* __restrict__ B2) {
    const int j = blockIdx.x;
    const int layer = blockIdx.y;
    const int k = threadIdx.x * 4;
    const float* Wl = layer ? W2l : W1l;
    const float* Wr = layer ? W2r : W1r;
    unsigned short* B = layer ? B2 : B1;
    const float4 v = (k < DD) ? *(const float4*)(Wl + (size_t)j * DD + k)
                              : *(const float4*)(Wr + (size_t)j * DD + (k - DD));
    ushort4 o; o.x = f2bf(v.x); o.y = f2bf(v.y); o.z = f2bf(v.z); o.w = f2bf(v.w);
    *(ushort4*)(B + (size_t)j * KC + k) = o;
}

// ---------------- CSR build (by dst) ----------------

__global__ __launch_bounds__(256) void k_hist(const int* __restrict__ dst,
                                              int* __restrict__ cnt) {
    int e = blockIdx.x * 256 + threadIdx.x;
    if (e < NE) atomicAdd(&cnt[dst[e]], 1);
}

// hierarchical scan, stage 1: per-block inclusive scan of 256-elem chunks
__global__ __launch_bounds__(256) void k_scan1(const int* __restrict__ cnt,
                                               int* __restrict__ rowptr,
                                               int* __restrict__ partial) {
    __shared__ int buf[256];
    const int t = threadIdx.x;
    const int i = blockIdx.x * 256 + t;
    int v = (i < NN) ? cnt[i] : 0;
    buf[t] = v;
    __syncthreads();
#pragma unroll
    for (int off = 1; off < 256; off <<= 1) {
        int u = (t >= off) ? buf[t - off] : 0;
        __syncthreads();
        buf[t] += u;
        __syncthreads();
    }
    if (i < NN) rowptr[i + 1] = buf[t];
    if (t == 255) partial[blockIdx.x] = buf[255];
}

// stage 2: single block, exclusive scan of SCAN_B partials
__global__ __launch_bounds__(256) void k_scan2(int* __restrict__ partial) {
    __shared__ int buf[256];
    const int t = threadIdx.x;
    int v = (t < SCAN_B) ? partial[t] : 0;
    buf[t] = v;
    __syncthreads();
#pragma unroll
    for (int off = 1; off < 256; off <<= 1) {
        int u = (t >= off) ? buf[t - off] : 0;
        __syncthreads();
        buf[t] += u;
        __syncthreads();
    }
    if (t < SCAN_B) partial[t] = buf[t] - v;  // exclusive
}

// stage 3: add block offsets, set rowptr[0]
__global__ __launch_bounds__(256) void k_scan3(int* __restrict__ rowptr,
                                               const int* __restrict__ partial) {
    const int i = blockIdx.x * 256 + threadIdx.x;
    if (i < NN) rowptr[i + 1] += partial[blockIdx.x];
    if (i == 0) rowptr[0] = 0;
}

__global__ __launch_bounds__(256) void k_fill(const int* __restrict__ src,
                                              const int* __restrict__ dst,
                                              const int* __restrict__ rowptr,
                                              int* __restrict__ cursor,
                                              int* __restrict__ esrc) {
    int e = blockIdx.x * 256 + threadIdx.x;
    if (e < NE) {
        const int d = dst[e];
        const int pos = atomicAdd(&cursor[d], 1);
        esrc[rowptr[d] + pos] = src[e];
    }
}

// ---------------- aggregation by gather (no atomics) ----------------
// Round 8: edge loop unrolled x2 with both row-gathers issued before the
// accumulation — the serial chain (esrc load -> row gather, ~500cy each)
// halves. Tail handled separately.
__global__ __launch_bounds__(192) void k_agg(const unsigned short* __restrict__ srcmat,
                                             const int* __restrict__ rowptr,
                                             const int* __restrict__ esrc,
                                             unsigned short* __restrict__ dstmat) {
    const int n = blockIdx.x;
    const int c = threadIdx.x * 4;
    const int beg = rowptr[n], end = rowptr[n + 1];
    float4 a = {0.f, 0.f, 0.f, 0.f};
    int e = beg;
    for (; e + 1 < end; e += 2) {
        const int s0 = esrc[e];
        const int s1 = esrc[e + 1];
        const ushort4 v0 = *(const ushort4*)(srcmat + (size_t)s0 * KC + DD + c);
        const ushort4 v1 = *(const ushort4*)(srcmat + (size_t)s1 * KC + DD + c);
        a.x += bf2f(v0.x) + bf2f(v1.x);
        a.y += bf2f(v0.y) + bf2f(v1.y);
        a.z += bf2f(v0.z) + bf2f(v1.z);
        a.w += bf2f(v0.w) + bf2f(v1.w);
    }
    if (e < end) {
        const int s = esrc[e];
        const ushort4 v = *(const ushort4*)(srcmat + (size_t)s * KC + DD + c);
        a.x += bf2f(v.x); a.y += bf2f(v.y); a.z += bf2f(v.z); a.w += bf2f(v.w);
    }
    const float inv = (end > beg) ? 1.0f / (float)(end - beg) : 1.0f;
    ushort4 o;
    o.x = f2bf(a.x * inv); o.y = f2bf(a.y * inv);
    o.z = f2bf(a.z * inv); o.w = f2bf(a.w * inv);
    *(ushort4*)(dstmat + (size_t)n * KC + c) = o;
}

// ---------------- GEMM: C[M x 768] = A[M x 1536] * B[768 x 1536]^T + bias ----
// Round 8: overlap fix. r7 (barrier diet) gave only 191->180us; decomposition
// of the 3930cyc K-tile: MFMA 1242 (per SIMD) + LDS-port 1536 (128 b128
// reads/CU x 12cyc) + sync — reads and MFMA are ADDING, not overlapping.
// Suspect: setprio(1) around the monolithic 32-MFMA cluster suppresses the
// SIMD-mate's ds_read issue (SQ arbitration favors prio-1 wave for ALL
// slots), serializing LDS-phase and MFMA-phase across the CU. Catalog: T5 is
// positive only in fine-grained phase-split schedules (m218b), null-to-neg
// on monolithic clusters (m190). Fix: DROP setprio; split the segment into
// two half-steps (reads ksub0 -> stage -> 16 MFMA -> reads ksub1 -> 16 MFMA)
// so each wave alternates port/pipe at half-tile granularity and SIMD-mates
// slip into complementary phases.
// Carried from r6/r7: 3 K-tile slots, stage-2-ahead, ONE vmcnt(6)+barrier
// per K-tile (never 0 mid-loop), chunk-XOR swizzle (conflicts 0), XCD-chunked
// tn-fast map (FETCH 126MB), 128x256 tile, 8 waves (2Mx4N), wave-tile 64x64.
// MODE 0: +bias, relu, store bf16 into right half of Acat2
// MODE 1: +bias, store f32 to out
template <int MODE>
__global__ __launch_bounds__(512) void k_gemm(const unsigned short* __restrict__ A,
                                              const unsigned short* __restrict__ B,
                                              const float* __restrict__ bias,
                                              unsigned short* __restrict__ outA,
                                              float* __restrict__ outF) {
    // 3 K-tile slots: A 128x64 (16KB) + B 256x64 (32KB) each -> 144KB total
    __shared__ alignas(16) unsigned short sA[3][BM * BK];
    __shared__ alignas(16) unsigned short sB[3][BN * BK];
    const int tid = threadIdx.x;
    const int w = tid >> 6, lane = tid & 63;
    const int quad = lane >> 4, r16 = lane & 15;
    const int wr = w >> 2, wc = w & 3;      // 2M x 4N wave grid
    const int wm = wr * 64, wn = wc * 64;   // wave-tile 64x64

    // bijective XCD-aware remap (m204); tn fast (3 blocks share one A-panel)
    const int nwg = NTM * NTN;              // 1173
    const int q = nwg >> 3, r = nwg & 7;
    const int xcd = blockIdx.x & 7, slot = blockIdx.x >> 3;
    const int L = (xcd < r ? xcd * (q + 1) : r * (q + 1) + (xcd - r) * q) + slot;
    const int tn = L % NTN;
    const int tm = L / NTN;
    const int rowBase = tm * BM;

    floatx4 acc[4][4];
#pragma unroll
    for (int i = 0; i < 4; ++i)
#pragma unroll
        for (int j = 0; j < 4; ++j) acc[i][j] = (floatx4){0.f, 0.f, 0.f, 0.f};

    // staging source pointers, pre-swizzled (m173): chunk c = l*512+tid,
    // row = c>>3, physical col-chunk (c&7) receives global chunk (c&7)^(row&7)
    const unsigned short* aS[2];
    const unsigned short* bS[4];
#pragma unroll
    for (int l = 0; l < 2; ++l) {
        const int c = l * 512 + tid;
        const int row = c >> 3;
        const int jd = ((c & 7) ^ (row & 7)) * 8;
        int gr = rowBase + row; if (gr > NN - 1) gr = NN - 1;  // clamp tail tile
        aS[l] = A + (size_t)gr * KC + jd;
    }
#pragma unroll
    for (int l = 0; l < 4; ++l) {
        const int c = l * 512 + tid;
        const int row = c >> 3;
        const int jd = ((c & 7) ^ (row & 7)) * 8;
        bS[l] = B + (size_t)(tn * BN + row) * KC + jd;
    }

    // stage one full K-tile into slot d: 6 gld16 per lane, then advance K
    auto stageK = [&](int d) {
        gld16(aS[0], &sA[d][(0 * 512 + w * 64) * 8]);
        gld16(aS[1], &sA[d][(1 * 512 + w * 64) * 8]);
        gld16(bS[0], &sB[d][(0 * 512 + w * 64) * 8]);
        gld16(bS[1], &sB[d][(1 * 512 + w * 64) * 8]);
        gld16(bS[2], &sB[d][(2 * 512 + w * 64) * 8]);
        gld16(bS[3], &sB[d][(3 * 512 + w * 64) * 8]);
        aS[0] += BK; aS[1] += BK;
        bS[0] += BK; bS[1] += BK; bS[2] += BK; bS[3] += BK;
    };

    const int pc0 = ((0 * 4 + quad) ^ (r16 & 7)) * 8;  // swizzled chunk, ksub 0
    const int pc1 = ((1 * 4 + quad) ^ (r16 & 7)) * 8;  // swizzled chunk, ksub 1

    // one K-tile segment in two half-steps; no setprio, no internal fences.
    auto seg = [&](int s, int d, int doStage) {
        bf16x8 a0[4], b0[4];
#pragma unroll
        for (int mf = 0; mf < 4; ++mf)
            a0[mf] = *(const bf16x8*)(&sA[s][(wm + mf * 16 + r16) * BK + pc0]);
#pragma unroll
        for (int nf = 0; nf < 4; ++nf)
            b0[nf] = *(const bf16x8*)(&sB[s][(wn + nf * 16 + r16) * BK + pc0]);
        if (doStage) stageK(d);
#pragma unroll
        for (int mf = 0; mf < 4; ++mf)
#pragma unroll
            for (int nf = 0; nf < 4; ++nf)
                acc[mf][nf] = __builtin_amdgcn_mfma_f32_16x16x32_bf16(a0[mf], b0[nf], acc[mf][nf], 0, 0, 0);
        bf16x8 a1[4], b1[4];
#pragma unroll
        for (int mf = 0; mf < 4; ++mf)
            a1[mf] = *(const bf16x8*)(&sA[s][(wm + mf * 16 + r16) * BK + pc1]);
#pragma unroll
        for (int nf = 0; nf < 4; ++nf)
            b1[nf] = *(const bf16x8*)(&sB[s][(wn + nf * 16 + r16) * BK + pc1]);
#pragma unroll
        for (int mf = 0; mf < 4; ++mf)
#pragma unroll
            for (int nf = 0; nf < 4; ++nf)
                acc[mf][nf] = __builtin_amdgcn_mfma_f32_16x16x32_bf16(a1[mf], b1[nf], acc[mf][nf], 0, 0, 0);
    };

    // boundary: counted drain (tile about to be read is resident; next
    // tile's 6 loads stay in flight) + single workgroup barrier.
#define BND(N)                                            \
    do {                                                  \
        __builtin_amdgcn_sched_barrier(0);                \
        asm volatile("s_waitcnt vmcnt(" #N ")" ::: "memory"); \
        __builtin_amdgcn_s_barrier();                     \
    } while (0)

    // 24 K-tiles, slot = t%3, staging targets slot (t+2)%3.
    stageK(0); stageK(1);  // tiles 0,1 (12 loads in flight)
#pragma unroll 1
    for (int g = 0; g < 7; ++g) {       // t = 0..20
        BND(6); seg(0, 2, 1);
        BND(6); seg(1, 0, 1);
        BND(6); seg(2, 1, 1);
    }
    BND(6); seg(0, 2, 1);   // t=21: stages tile 23 -> slot 2
    BND(6); seg(1, 0, 0);   // t=22
    BND(0); seg(2, 0, 0);   // t=23: final tile (drain all)
#undef BND

    // epilogue: C/D layout col=lane&15, row=quad*4+reg
#pragma unroll
    for (int mf = 0; mf < 4; ++mf)
#pragma unroll
        for (int nf = 0; nf < 4; ++nf) {
            const int gcol = tn * BN + wn + nf * 16 + r16;
            const float bv = bias[gcol];
#pragma unroll
            for (int rr = 0; rr < 4; ++rr) {
                const int grow = rowBase + wm + mf * 16 + quad * 4 + rr;
                if (grow < NN) {
                    float v = acc[mf][nf][rr] + bv;
                    if (MODE == 0) {
                        v = fmaxf(v, 0.0f);
                        outA[(size_t)grow * KC + DD + gcol] = f2bf(v);
                    } else {
                        outF[(size_t)grow * DD + gcol] = v;
                    }
                }
            }
        }
}

extern "C" void kernel_launch(void* const* d_in, const int* in_sizes, int n_in,
                              void* d_out, int out_size, void* d_ws, size_t ws_size,
                              hipStream_t stream) {
    const float* x   = (const float*)d_in[0];
    const int*   ei  = (const int*)d_in[1];
    const float* W1l = (const float*)d_in[2];
    const float* b1l = (const float*)d_in[3];
    const float* W1r = (const float*)d_in[4];
    const float* W2l = (const float*)d_in[5];
    const float* b2l = (const float*)d_in[6];
    const float* W2r = (const float*)d_in[7];
    const int* src = ei;
    const int* dst = ei + NE;
    float* out = (float*)d_out;

    // ws layout (~310 MB):
    //   Acat1: [N x 1536] bf16  (left=agg1, right=bf16(x))
    //   Acat2: [N x 1536] bf16  (left=agg2, right=h)
    //   B1,B2: [768 x 1536] bf16 each
    //   CSR:   cnt[N] (reused as cursor), rowptr[N+1], esrc[E], partial[SCAN_B]
    char* ws = (char*)d_ws;
    unsigned short* Acat1 = (unsigned short*)ws;
    unsigned short* Acat2 = (unsigned short*)(ws + (size_t)NN * KC * 2);
    unsigned short* B1    = (unsigned short*)(ws + (size_t)NN * KC * 4);
    unsigned short* B2    = B1 + (size_t)DD * KC;
    int* cnt    = (int*)(ws + (size_t)NN * KC * 4 + (size_t)DD * KC * 4);
    int* rowptr = cnt + NN;
    int* esrc   = rowptr + NN + 1;
    int* partial = esrc + NE;

    // CSR build (hierarchical scan; no single-block serialization)
    hipMemsetAsync(cnt, 0, NN * sizeof(int), stream);
    k_hist<<<(NE + 255) / 256, 256, 0, stream>>>(dst, cnt);
    k_scan1<<<SCAN_B, 256, 0, stream>>>(cnt, rowptr, partial);
    k_scan2<<<1, 256, 0, stream>>>(partial);
    k_scan3<<<SCAN_B, 256, 0, stream>>>(rowptr, partial);
    hipMemsetAsync(cnt, 0, NN * sizeof(int), stream);  // reuse as cursor
    k_fill<<<(NE + 255) / 256, 256, 0, stream>>>(src, dst, rowptr, cnt, esrc);

    // converts
    k_convert_x<<<NN, 192, 0, stream>>>(x, Acat1);
    dim3 wgrid(DD, 2);
    k_convert_w<<<wgrid, 384, 0, stream>>>(W1l, W1r, W2l, W2r, B1, B2);

    const int ggrid = NTM * NTN;  // 1173 blocks, XCD-chunked tn-fast mapping inside

    // layer 1 (aggregate bf16(x) from right half of Acat1)
    k_agg<<<NN, 192, 0, stream>>>(Acat1, rowptr, esrc, Acat1);
    k_gemm<0><<<ggrid, 512, 0, stream>>>(Acat1, B1, b1l, Acat2, nullptr);

    // layer 2
    k_agg<<<NN, 192, 0, stream>>>(Acat2, rowptr, esrc, Acat2);
    k_gemm<1><<<ggrid, 512, 0, stream>>>(Acat2, B2, b2l, nullptr, out);
}